// Round 1
// baseline (266.892 us; speedup 1.0000x reference)
//
#include <hip/hip_runtime.h>
#include <math.h>

// Problem constants (from reference):
//   N_WIDTH=128, N_ORDER=4, N_ELEMENTS=128, N_NODES=513, X in [0,1]
//   delta = 0.5*4*1/512 = 1/256  ->  1/delta = 256, 1/delta^2 = 65536
// Output: [3, 1, 128, 513] float32 = slices of phi/dphi/ddphi buffers at
// [sample], with 5 columns per row overwritten by Lagrange p / dp/delta /
// ddp/delta^2. x is scalar -> same values and columns for every row.

#define PHI_W     128
#define PHI_NN    513
#define PHI_ORD   4
#define PHI_PER   (PHI_W * PHI_NN)      /* 65664 */
#define PHI_TOTAL (3 * PHI_PER)         /* 196992 */

__global__ __launch_bounds__(256) void phi_kernel(
    const float* __restrict__ x_ptr,
    const float* __restrict__ phi_in,
    const float* __restrict__ dphi_in,
    const float* __restrict__ ddphi_in,
    const int*   __restrict__ sample_ptr,
    float*       __restrict__ out)
{
    int idx = blockIdx.x * blockDim.x + threadIdx.x;
    if (idx >= PHI_TOTAL) return;

    int k   = idx / PHI_PER;            // 0=phi, 1=dphi, 2=ddphi
    int rem = idx - k * PHI_PER;        // w*513 + c
    int c   = rem % PHI_NN;

    int sample = sample_ptr[0];
    const float* buf = (k == 0) ? phi_in : ((k == 1) ? dphi_in : ddphi_in);
    float val = buf[(size_t)sample * PHI_PER + rem];   // pass-through value

    // Element / local-coordinate math (all rows share scalar x)
    float x       = x_ptr[0];
    float x_shift = 512.0f * x;                        // (N_NODES-1)*(x-0)/1
    int   id_el   = (int)floorf(x_shift * 0.25f);      // floor(x_shift/N_ORDER)
    id_el = min(max(id_el, 0), 127);                   // clip to N_ELEMENTS-1
    int   nodes_l = id_el * PHI_ORD;
    int   j       = c - nodes_l;                       // local basis index

    if (j >= 0 && j <= PHI_ORD) {
        float xt = (x_shift - (float)(nodes_l + 2)) * 0.5f;
        // nodes = linspace(-1,1,5) = {-1,-0.5,0,0.5,1}; nodes[j] = -1 + 0.5*j
        float nj = -1.0f + 0.5f * (float)j;
        float ratio[5];   // ratio[m] = (xt-nodes[m])/(nodes[j]-nodes[m]); ratio[j]=1
        float invjm[5];   // 1/(nodes[j]-nodes[m]); invjm[j]=0
        #pragma unroll
        for (int m = 0; m < 5; ++m) {
            float nm = -1.0f + 0.5f * (float)m;
            if (m == j) { ratio[m] = 1.0f; invjm[m] = 0.0f; }
            else {
                float inv = 1.0f / (nj - nm);
                invjm[m] = inv;
                ratio[m] = (xt - nm) * inv;
            }
        }
        if (k == 0) {
            // p_j = prod_{m != j} ratio[m]   (ratio[j]==1 makes this a full prod)
            float p = 1.0f;
            #pragma unroll
            for (int m = 0; m < 5; ++m) p *= ratio[m];
            val = p;
        } else if (k == 1) {
            // dp_j = sum_{i != j} inv[j,i] * prod_{m != i,j} ratio[m]
            float dp = 0.0f;
            #pragma unroll
            for (int i = 0; i < 5; ++i) {
                if (i == j) continue;
                float pr = 1.0f;
                #pragma unroll
                for (int m = 0; m < 5; ++m)
                    if (m != i) pr *= ratio[m];   // ratio[j]==1 excludes j
                dp += invjm[i] * pr;
            }
            val = dp * 256.0f;                    // dp / delta
        } else {
            // ddp_j = sum_{i!=j} inv[j,i] * sum_{m!=i,j} inv[j,m] * prod_{n!=i,j,m} ratio[n]
            float ddp = 0.0f;
            #pragma unroll
            for (int i = 0; i < 5; ++i) {
                if (i == j) continue;
                float inner = 0.0f;
                #pragma unroll
                for (int m = 0; m < 5; ++m) {
                    if (m == i || m == j) continue;
                    float pr = 1.0f;
                    #pragma unroll
                    for (int n = 0; n < 5; ++n)
                        if (n != i && n != m) pr *= ratio[n];  // ratio[j]==1 excludes j
                    inner += invjm[m] * pr;
                }
                ddp += invjm[i] * inner;
            }
            val = ddp * 65536.0f;                 // ddp / delta^2
        }
    }
    out[idx] = val;
}

extern "C" void kernel_launch(void* const* d_in, const int* in_sizes, int n_in,
                              void* d_out, int out_size, void* d_ws, size_t ws_size,
                              hipStream_t stream) {
    (void)in_sizes; (void)n_in; (void)out_size; (void)d_ws; (void)ws_size;
    const float* x      = (const float*)d_in[0];
    const float* phi    = (const float*)d_in[1];
    const float* dphi   = (const float*)d_in[2];
    const float* ddphi  = (const float*)d_in[3];
    const int*   sample = (const int*)d_in[4];
    // d_in[5] = epoch, unused by the reference forward.
    float* out = (float*)d_out;

    const int threads = 256;
    const int blocks  = (PHI_TOTAL + threads - 1) / threads;  // 770
    phi_kernel<<<blocks, threads, 0, stream>>>(x, phi, dphi, ddphi, sample, out);
}